// Round 9
// baseline (3313.641 us; speedup 1.0000x reference)
//
#include <hip/hip_runtime.h>
#include <hip/hip_bf16.h>
#include <hip/hip_fp16.h>

// LSTM_RNN: B=128, T=512, E=256, U=512. R23 = R22 − B2 − LDS staging:
// per-lane DIRECT L2 GATHER of h into MFMA fragments; 1 barrier/step.
//   R22 (1766us steady, matched prediction): B4 removal -> -0.75us/step.
//   Remaining 3.45us/step chain includes bulk(400cy)+LDS stage(150)+B2
//   (200) whose only job is redistributing h from "4 rows/wave" to "row
//   p16/lane". But lane (p16,quad) of wave-group kh needs exactly 16x8B
//   at Hq_row(p16) + (kh*16+i)*32B + quad*8B — gatherable DIRECTLY from
//   the XCD-L2 with one asm block of pipelined sc0 loads (same proven
//   mechanism as R17-R22's bulk block). So:
//   - Hs slab + bulk + stage + B2 DELETED. h-GEMM A-frags come straight
//     from Hq (sc0, imm offsets 0..480B off one per-lane base).
//   - Gate: wave0 (kh0) polls flags (R21 RMW budget-6 + agent fallback),
//     sets LDS goP=t; ALL other 7 waves spin goP>=t (address-dependency
//     pinned via dep=gv>>16, as before).
//   - Rs parity-double-buffered [2][4][512]f -> B2's Rs-WAR role gone:
//     kh1 rewrites parity p only after B3(t+1), which happens-after kh0's
//     epilogue(t) reads (barrier rendezvous).
//   - Hq WAR: reads of parity p at step t precede B3(t) (program order);
//     any WG's writes of parity p at epilogue(t+1) follow its gate(t+1),
//     and flags==t+1 imply every domain WG passed B3(t) -> publish/gate
//     induction unchanged (R14-R22).
//   - goP monotone: wave0 can't set t+1 before B3(t) retires spinners.
//   - Publish R22-verbatim: per-wave vmcnt(0) drain + LDS pcnt; 4th
//     arrival publishes FlagA (atomic swap, L2) + FlagB (agent).
// ws layout (~33.82 MiB):
//   X      fp16 [T][B][E]        @ 0          (33,554,432 B)
//   Hq     fp16 [2][8][16][512]  @ 33,554,432 (262,144 B)
//   FlagA  u32  [2][8][16]       @ 33,816,576 (1,024 B)  atomic/L2 channel
//   FlagB  u32  [2][8][16]       @ 33,817,600 (1,024 B)  agent/LLC channel
//   XccTab u32  [128]            @ 33,818,624 (512 B)
//   (FlagA..XccTab = 2,560 B contiguous, memset 0 each launch)

#define B_ 128
#define T_ 512
#define E_ 256
#define U_ 512
#define NWG_ 128

typedef __attribute__((ext_vector_type(4))) _Float16 half4;
typedef __attribute__((ext_vector_type(4))) float floatx4;
typedef unsigned long long u64t;
typedef unsigned int u32t;

#define MFMA16 __builtin_amdgcn_mfma_f32_16x16x16f16

__device__ __forceinline__ float sigmf(float x) { return 1.0f / (1.0f + __expf(-x)); }
__device__ __forceinline__ float tanh_f(float x) { return 2.0f / (1.0f + __expf(-2.0f * x)) - 1.0f; }

// X[t][b][e] = (fp16) emb[sentence[b][t]][e]; one thread = 8 elements.
__global__ void prep_x_kernel(const int* __restrict__ sent,
                              const float* __restrict__ emb,
                              _Float16* __restrict__ X) {
  int gid = blockIdx.x * blockDim.x + threadIdx.x;  // 2,097,152 total
  int e8 = gid & 31;
  int row = gid >> 5;         // row = t*128 + b
  int b = row & 127;
  int t = row >> 7;
  int word = sent[b * T_ + t];
  const float* src = emb + (size_t)word * E_ + e8 * 8;
  float4 v0 = *(const float4*)(src);
  float4 v1 = *(const float4*)(src + 4);
  _Float16 o[8] = {(_Float16)v0.x, (_Float16)v0.y, (_Float16)v0.z, (_Float16)v0.w,
                   (_Float16)v1.x, (_Float16)v1.y, (_Float16)v1.z, (_Float16)v1.w};
  _Float16* dst = X + (size_t)row * E_ + e8 * 8;
  *(half4*)dst = *(half4*)o;
  *(half4*)(dst + 4) = *(half4*)(o + 4);
}

__global__ __launch_bounds__(512, 1) void lstm_kernel(
    const _Float16* __restrict__ X,
    const float* __restrict__ Wx, const float* __restrict__ Wh,
    const float* __restrict__ bias,
    _Float16* __restrict__ Hq, u32t* FlagA, u32t* FlagB, u32t* XccTab) {
  // LDS: Rs float[2][4][512] (16,384) | xl u32[128] (512) | go u32 |
  // pcnt u32 = 16,904 used; block padded to 96 KB -> 1 wg/CU.
  __shared__ __align__(16) char smem[98304];
  float* Rs = (float*)smem;
  u32t* xl = (u32t*)(smem + 16384);
  volatile u32t* goP = (volatile u32t*)(smem + 16896);
  u32t* pcntP = (u32t*)(smem + 16900);

  const int bid = blockIdx.x;
  const int d = bid & 7;    // domain: rows d*16 .. d*16+15 (one XCD, verified)
  const int s = bid >> 3;   // unit slice: units s*32 .. s*32+31
  const int tid = threadIdx.x;
  const int lane = tid & 63;
  const int wave = tid >> 6;      // 8 waves
  const int p16 = lane & 15;
  const int quad = lane >> 4;
  const int sg = wave & 3;        // unit subgroup (8 units)
  const int kh = wave >> 2;       // 0: gate + h[0,256) + epilogue
                                  // 1: x-GEMM + h[256,512)

  // ---- one-time XCD-mapping probe (gates the L2-local DATA path) ----
  // hwreg(HW_REG_XCC_ID=20, offset=0, size=32) -> imm = (31<<11)|20 = 63508
  if (tid == 0) {
    *goP = 0u;
    *pcntP = 0u;
    u32t myx = (u32t)__builtin_amdgcn_s_getreg(63508) & 0xFFu;
    __hip_atomic_store(XccTab + bid, 0x5A5A0000u | myx, __ATOMIC_RELAXED,
                       __HIP_MEMORY_SCOPE_AGENT);
  }
  if (wave == 0) {
    u32t v0, v1;
    for (;;) {
      v0 = __hip_atomic_load(XccTab + lane, __ATOMIC_RELAXED,
                             __HIP_MEMORY_SCOPE_AGENT);
      v1 = __hip_atomic_load(XccTab + 64 + lane, __ATOMIC_RELAXED,
                             __HIP_MEMORY_SCOPE_AGENT);
      if (__all(((v0 >> 16) == 0x5A5Au) & ((v1 >> 16) == 0x5A5Au))) break;
      __builtin_amdgcn_s_sleep(8);
    }
    xl[lane] = v0;
    xl[lane + 64] = v1;
  }
  __syncthreads();
  int fastv;
  {
    const u32t ref = xl[d];
    bool dom = true;
    for (int j = 1; j < 16; ++j) dom = dom && (xl[d + 8 * j] == ref);
    bool sane = false;  // getreg sanity: a constant-reading getreg -> slow
    const u32t z0 = xl[0];
    for (int e = 1; e < 128; ++e) sane = sane || (xl[e] != z0);
    fastv = (dom && sane) ? 1 : 0;
  }
  const bool fastp = (bool)__builtin_amdgcn_readfirstlane(fastv);

  // ---- one-time: gather this wave's B-fragments into VGPRs ----
  // kh0: 16 h-blocks (cols 0..255)   -> b0r[i], kb = 16+i,  i in [0,16)
  // kh1: 16 x-blocks + 16 h-blocks (cols 256..511)
  //      -> b0r[i]: i<16: kb = i (x); i>=16: kb = 16+i (h hi), i in [0,32)
  const int C0 = ((p16 >> 3) & 1) * 512 + s * 32 + sg * 8 + (p16 & 7);  // i/f
  const int C1 = C0 + 1024;                                             // g/o
  half4 b0r[32], b1r[32];
  if (kh == 0) {
#pragma unroll
    for (int i = 0; i < 16; ++i) {
      int kb = 16 + i;
#pragma unroll
      for (int j = 0; j < 4; ++j) {
        int gk = kb * 16 + quad * 4 + j;
        b0r[i][j] = (_Float16)Wh[(size_t)(gk - E_) * 2048 + C0];
        b1r[i][j] = (_Float16)Wh[(size_t)(gk - E_) * 2048 + C1];
      }
    }
  } else {
#pragma unroll
    for (int i = 0; i < 32; ++i) {
      int kb = (i < 16) ? i : (16 + i);
#pragma unroll
      for (int j = 0; j < 4; ++j) {
        int gk = kb * 16 + quad * 4 + j;
        float w0 = (gk < E_) ? Wx[(size_t)gk * 2048 + C0]
                             : Wh[(size_t)(gk - E_) * 2048 + C0];
        float w1 = (gk < E_) ? Wx[(size_t)gk * 2048 + C1]
                             : Wh[(size_t)(gk - E_) * 2048 + C1];
        b0r[i][j] = (_Float16)w0;
        b1r[i][j] = (_Float16)w1;
      }
    }
  }

  const bool lo = (p16 < 8);
  const int uo = p16 & 7;
  const int gu = s * 32 + sg * 8 + uo;               // global unit id
  const float bias0 = bias[(lo ? 0 : 512) + gu];     // i or f
  const float bias1 = bias[(lo ? 1024 : 1536) + gu]; // g or o

  float cst[4] = {0.f, 0.f, 0.f, 0.f};  // c-state (kh0 waves, lo lanes)

  const int brow = d * 16 + p16;   // A-frag batch row
  const int ko = quad * 4;

  for (int t = 0; t < T_; ++t) {
    const int pin = t & 1, pout = pin ^ 1;

    floatx4 acc0 = {0.f, 0.f, 0.f, 0.f};
    floatx4 acc1 = {0.f, 0.f, 0.f, 0.f};

    if (kh == 1) {
      // ---- x-GEMM (kh1 only): 16 K16-blocks ----
      const _Float16* xr = X + ((size_t)t * B_ + brow) * E_ + ko;
#pragma unroll
      for (int i = 0; i < 16; ++i) {
        half4 a = *(const half4*)(xr + i * 16);
        acc0 = MFMA16(a, b0r[i], acc0, 0, 0, 0);
        acc1 = MFMA16(a, b1r[i], acc1, 0, 0, 0);
      }
    }

    if (t > 0) {
      // ---- gate ----
      const u32t tgt = (u32t)t;
      u32t gv;
      if (wave == 0) {
        // wave 0 (kh0) is the sole flag poller (16 lanes, 16 words).
        u32t v;
        if (fastp) {
          u32t* fa = FlagA + (size_t)(pin * 8 + d) * 16;
          const u32t* fb = FlagB + (size_t)(pin * 8 + d) * 16;
          int budget = 6;
          for (;;) {
            if (budget > 0) {
              // atomic RMW add-0 sc0: executes at the owning cache.
              u32t old = tgt;
              if (lane < 16) {
                u32t* ap = fa + lane;
                asm volatile(
                    "global_atomic_add %0, %1, %2, off sc0\n\t"
                    "s_waitcnt vmcnt(0)"
                    : "=&v"(old) : "v"(ap), "v"(0u) : "memory");
              }
              v = old;
            } else {
              v = (lane < 16)
                      ? __hip_atomic_load(fb + lane, __ATOMIC_RELAXED,
                                          __HIP_MEMORY_SCOPE_AGENT)
                      : tgt;
            }
            if (__all(v == tgt)) break;
            --budget;
            if (budget < 4) __builtin_amdgcn_s_sleep(1);
          }
        } else {
          const u32t* fb = FlagB + (size_t)(pin * 8 + d) * 16;
          for (;;) {
            v = (lane < 16)
                    ? __hip_atomic_load(fb + lane, __ATOMIC_RELAXED,
                                        __HIP_MEMORY_SCOPE_AGENT)
                    : tgt;
            if (__all(v == tgt)) break;
            __builtin_amdgcn_s_sleep(1);
          }
        }
        gv = v;             // == tgt on every lane
        if (lane == 0) *goP = tgt;   // LDS release for the other 7 waves
      } else {
        // waves 1-7: LDS gate (goP monotone; ==t exactly when released).
        u32t g;
        do { g = *goP; } while (g < tgt);
        gv = g;
      }
      const size_t dep = (size_t)(gv >> 16);  // always 0; addr dependency

      // ---- h-GEMM: per-lane direct L2 gather of A-frags ----
      // lane (p16,quad), group kh: 16 x 8B at row(p16) + (kh*16+i)*32B
      // + quad*8B. One base, imm offsets i*32, pipelined, one vmcnt.
      const _Float16* rowp =
          Hq + ((size_t)(pin * 8 + d) * 16 + p16) * 512 + kh * 256 + quad * 4 +
          dep;
      u64t hv[16];
      if (fastp) {
        const u64t* gb = (const u64t*)rowp;
        u64t h0, h1, h2, h3, h4, h5, h6, h7, h8, h9, hA, hB, hC, hD, hE, hF;
        asm volatile(
            "global_load_dwordx2 %0, %8, off sc0\n\t"
            "global_load_dwordx2 %1, %8, off offset:32 sc0\n\t"
            "global_load_dwordx2 %2, %8, off offset:64 sc0\n\t"
            "global_load_dwordx2 %3, %8, off offset:96 sc0\n\t"
            "global_load_dwordx2 %4, %8, off offset:128 sc0\n\t"
            "global_load_dwordx2 %5, %8, off offset:160 sc0\n\t"
            "global_load_dwordx2 %6, %8, off offset:192 sc0\n\t"
            "global_load_dwordx2 %7, %8, off offset:224 sc0"
            : "=&v"(h0), "=&v"(h1), "=&v"(h2), "=&v"(h3),
              "=&v"(h4), "=&v"(h5), "=&v"(h6), "=&v"(h7)
            : "v"(gb)
            : "memory");
        asm volatile(
            "global_load_dwordx2 %0, %8, off offset:256 sc0\n\t"
            "global_load_dwordx2 %1, %8, off offset:288 sc0\n\t"
            "global_load_dwordx2 %2, %8, off offset:320 sc0\n\t"
            "global_load_dwordx2 %3, %8, off offset:352 sc0\n\t"
            "global_load_dwordx2 %4, %8, off offset:384 sc0\n\t"
            "global_load_dwordx2 %5, %8, off offset:416 sc0\n\t"
            "global_load_dwordx2 %6, %8, off offset:448 sc0\n\t"
            "global_load_dwordx2 %7, %8, off offset:480 sc0\n\t"
            "s_waitcnt vmcnt(0)"
            : "=&v"(h8), "=&v"(h9), "=&v"(hA), "=&v"(hB),
              "=&v"(hC), "=&v"(hD), "=&v"(hE), "=&v"(hF)
            : "v"(gb)
            : "memory");
        hv[0] = h0; hv[1] = h1; hv[2] = h2; hv[3] = h3;
        hv[4] = h4; hv[5] = h5; hv[6] = h6; hv[7] = h7;
        hv[8] = h8; hv[9] = h9; hv[10] = hA; hv[11] = hB;
        hv[12] = hC; hv[13] = hD; hv[14] = hE; hv[15] = hF;
      } else {
#pragma unroll
        for (int j = 0; j < 16; ++j) {
          hv[j] = __hip_atomic_load((const u64t*)rowp + (size_t)j * 4,
                                    __ATOMIC_RELAXED,
                                    __HIP_MEMORY_SCOPE_AGENT);
        }
      }
#pragma unroll
      for (int i = 0; i < 16; ++i) {
        half4 a = __builtin_bit_cast(half4, hv[i]);
        const int wi = (kh == 0) ? i : (16 + i);
        acc0 = MFMA16(a, b0r[wi], acc0, 0, 0, 0);
        acc1 = MFMA16(a, b1r[wi], acc1, 0, 0, 0);
      }
    }

    // ---- kh1 partials -> Rs (parity-buffered: no B2 needed for WAR) ----
    if (kh == 1) {
      float* wb = Rs + pin * 2048 + sg * 512;
      *(floatx4*)(wb + lane * 4) = acc0;
      *(floatx4*)(wb + 256 + lane * 4) = acc1;
    }
    __syncthreads();  // B3: partials ready. kh1 then free-runs to t+1.

    // ---- epilogue (kh0): reduce, gates, fp16 publish, flag ----
    if (kh == 0) {
      const float* rb = Rs + pin * 2048 + sg * 512;
      floatx4 z0v = acc0 + *(const floatx4*)(rb + lane * 4);
      floatx4 z1v = acc1 + *(const floatx4*)(rb + 256 + lane * 4);
#pragma unroll
      for (int r = 0; r < 4; ++r) {
        float z0 = z0v[r] + bias0;  // i (lo) / f (hi)
        float z1 = z1v[r] + bias1;  // g (lo) / o (hi)
        float s0 = sigmf(z0);
        float s1 = lo ? tanh_f(z1) : sigmf(z1);
        float prod = s0 * s1;                          // i*g on lo lanes
        float fg = __shfl_xor(lo ? prod : s0, 8, 64);  // lo receives f
        float og = __shfl_xor(s1, 8, 64);              // lo receives o
        if (lo) {
          float cn = fg * cst[r] + prod;
          cst[r] = cn;
          float h = og * tanh_f(cn);
          int rowl = quad * 4 + r;                     // local row in domain
          _Float16 hf16 = (_Float16)h;
          unsigned short hb = __builtin_bit_cast(unsigned short, hf16);
          unsigned short* hp =
              (unsigned short*)(Hq +
                                ((size_t)(pout * 8 + d) * 16 + rowl) * 512 + gu);
          if (fastp) {
            // plain store: L1 write-through -> dirty in local XCD-L2
            *hp = hb;
          } else {
            __hip_atomic_store(hp, hb, __ATOMIC_RELAXED,
                               __HIP_MEMORY_SCOPE_AGENT);
          }
        }
      }

      // ---- publish: per-wave drain + LDS counter (R22-proven) ----
      asm volatile("s_waitcnt vmcnt(0)" ::: "memory");
      __builtin_amdgcn_sched_barrier(0);
      if (lane == 0) {
        u32t old = atomicAdd(pcntP, 1u);
        if (old == (u32t)(4 * t + 3)) {
          size_t fo = (size_t)(pout * 8 + d) * 16 + s;
          if (fastp) {
            u32t* ap = FlagA + fo;
            u32t nv = (u32t)(t + 1);
            asm volatile("global_atomic_swap %0, %1, off"
                         :: "v"(ap), "v"(nv) : "memory");
          }
          __hip_atomic_store(FlagB + fo, (u32t)(t + 1), __ATOMIC_RELAXED,
                             __HIP_MEMORY_SCOPE_AGENT);  // progress channel
        }
      }
    }
  }
}

// MLP head: one block per batch row. h(512)->relu 128->relu 64->sigmoid 1.
// T=512 even -> final h in Hq parity 0. Kernel boundary orders prior stores
// (end-of-dispatch agent release writes back dirty L2 lines).
__global__ void head_kernel(const _Float16* __restrict__ Hq,
                            const float* __restrict__ W1, const float* __restrict__ b1,
                            const float* __restrict__ W2, const float* __restrict__ b2,
                            const float* __restrict__ W3, const float* __restrict__ b3,
                            float* __restrict__ out) {
  __shared__ float hs[512];
  __shared__ float h1[128];
  __shared__ float h2[64];
  int row = blockIdx.x;
  int tid = threadIdx.x;  // 128 threads
  int dd = row >> 4, rr = row & 15;
  const _Float16* hrow = Hq + ((size_t)dd * 16 + rr) * 512;
  for (int k = tid; k < 512; k += 128) hs[k] = (float)hrow[k];
  __syncthreads();
  float a = b1[tid];
  for (int k = 0; k < 512; ++k) a += hs[k] * W1[k * 128 + tid];
  h1[tid] = fmaxf(a, 0.0f);
  __syncthreads();
  if (tid < 64) {
    float a2 = b2[tid];
    for (int k = 0; k < 128; ++k) a2 += h1[k] * W2[k * 64 + tid];
    h2[tid] = fmaxf(a2, 0.0f);
  }
  __syncthreads();
  if (tid == 0) {
    float a3 = b3[0];
    for (int k = 0; k < 64; ++k) a3 += h2[k] * W3[k];
    out[row] = 1.0f / (1.0f + __expf(-a3));
  }
}

extern "C" void kernel_launch(void* const* d_in, const int* in_sizes, int n_in,
                              void* d_out, int out_size, void* d_ws, size_t ws_size,
                              hipStream_t stream) {
  const int* sent = (const int*)d_in[0];
  const float* emb = (const float*)d_in[1];
  const float* Wx = (const float*)d_in[2];
  const float* Wh = (const float*)d_in[3];
  const float* b = (const float*)d_in[4];
  const float* W1 = (const float*)d_in[5];
  const float* b1 = (const float*)d_in[6];
  const float* W2 = (const float*)d_in[7];
  const float* b2 = (const float*)d_in[8];
  const float* W3 = (const float*)d_in[9];
  const float* b3 = (const float*)d_in[10];
  float* out = (float*)d_out;

  char* ws = (char*)d_ws;
  _Float16* X = (_Float16*)(ws);
  _Float16* Hq = (_Float16*)(ws + (size_t)33554432);
  u32t* FlagA = (u32t*)(ws + (size_t)33554432 + 262144);
  u32t* FlagB = (u32t*)(ws + (size_t)33554432 + 263168);
  u32t* XccTab = (u32t*)(ws + (size_t)33554432 + 264192);

  // Zero FlagA+FlagB+XccTab (contiguous 2,560 B) every launch:
  // removes the first-launch garbage hazard; 0 never matches t in [1,512].
  hipMemsetAsync(FlagA, 0, 2560, stream);
  prep_x_kernel<<<8192, 256, 0, stream>>>(sent, emb, X);
  lstm_kernel<<<NWG_, 512, 0, stream>>>(X, Wx, Wh, b, Hq, FlagA, FlagB, XccTab);
  head_kernel<<<128, 128, 0, stream>>>(Hq, W1, b1, W2, b2, W3, b3, out);
}

// Round 10
// 1775.657 us; speedup vs baseline: 1.8661x; 1.8661x over previous
//
#include <hip/hip_runtime.h>
#include <hip/hip_bf16.h>
#include <hip/hip_fp16.h>

// LSTM_RNN: B=128, T=512, E=256, U=512. R24 = R22 REVERT (R23's direct-L2
// gather REFUTED: uncoalesced 16-segment loads + 4x redundant reads after
// dropping the LDS broadcast -> 1766->3230us; keep coalesced bulk + LDS)
// + TRANSPOSED MFMA EPILOGUE + poll budget fix.
//   1) Operand-swap transpose: f16 MFMA A/B fragment layouts are symmetric
//      (A: row=lane&15, k=quad*4+j; B: col=lane&15, k=quad*4+j), so
//      mfma(W_frag, h_frag) computes z^T with BIT-IDENTICAL weight gather
//      and x/LDS reads. C layout becomes: col(lane&15)=batch row, reg
//      m=quad*4+r=gate-col via C(m)=(m>>3)*512+s*32+sg*8+(m&7). Epilogue:
//      quad0/1 lanes hold i(acc0),g(acc1), quad2/3 hold f,o for the SAME
//      units -> shfl_xor(32) pairs them; each quad<2 lane produces h for
//      4 CONSECUTIVE units of one row -> ONE packed 8B store (was 4x 2B
//      scalar stores/lane; 128->32 stores/wave) -> faster vmcnt drain
//      before publish.
//   2) Poll budget 6->512: R21 proved the RMW/L2 flag channel works; the
//      old budget-6 spill into ~900cy agent polls quantized observe
//      latency. Agent fallback kept as a (never-taken) hang guard.
//   Everything else R22-verbatim: 8 domains x 16 slices, XCC probe gating
//   sc0 data path, coalesced 8x512B bulk + LDS stage + B2, Rs partials +
//   B3, per-wave drain + LDS pcnt publish (no B4), FlagA atomic swap/RMW
//   + FlagB agent, memset-0 flags.
// ws layout (~33.82 MiB):
//   X      fp16 [T][B][E]        @ 0          (33,554,432 B)
//   Hq     fp16 [2][8][16][512]  @ 33,554,432 (262,144 B)
//   FlagA  u32  [2][8][16]       @ 33,816,576 (1,024 B)  atomic/L2 channel
//   FlagB  u32  [2][8][16]       @ 33,817,600 (1,024 B)  agent/LLC channel
//   XccTab u32  [128]            @ 33,818,624 (512 B)
//   (FlagA..XccTab = 2,560 B contiguous, memset 0 each launch)

#define B_ 128
#define T_ 512
#define E_ 256
#define U_ 512
#define NWG_ 128
#define HROW_ 516   // Hs row stride (halves)

typedef __attribute__((ext_vector_type(4))) _Float16 half4;
typedef __attribute__((ext_vector_type(4))) float floatx4;
typedef unsigned long long u64t;
typedef unsigned int u32t;

#define MFMA16 __builtin_amdgcn_mfma_f32_16x16x16f16

__device__ __forceinline__ float sigmf(float x) { return 1.0f / (1.0f + __expf(-x)); }
__device__ __forceinline__ float tanh_f(float x) { return 2.0f / (1.0f + __expf(-2.0f * x)) - 1.0f; }

// X[t][b][e] = (fp16) emb[sentence[b][t]][e]; one thread = 8 elements.
__global__ void prep_x_kernel(const int* __restrict__ sent,
                              const float* __restrict__ emb,
                              _Float16* __restrict__ X) {
  int gid = blockIdx.x * blockDim.x + threadIdx.x;  // 2,097,152 total
  int e8 = gid & 31;
  int row = gid >> 5;         // row = t*128 + b
  int b = row & 127;
  int t = row >> 7;
  int word = sent[b * T_ + t];
  const float* src = emb + (size_t)word * E_ + e8 * 8;
  float4 v0 = *(const float4*)(src);
  float4 v1 = *(const float4*)(src + 4);
  _Float16 o[8] = {(_Float16)v0.x, (_Float16)v0.y, (_Float16)v0.z, (_Float16)v0.w,
                   (_Float16)v1.x, (_Float16)v1.y, (_Float16)v1.z, (_Float16)v1.w};
  _Float16* dst = X + (size_t)row * E_ + e8 * 8;
  *(half4*)dst = *(half4*)o;
  *(half4*)(dst + 4) = *(half4*)(o + 4);
}

__global__ __launch_bounds__(512, 1) void lstm_kernel(
    const _Float16* __restrict__ X,
    const float* __restrict__ Wx, const float* __restrict__ Wh,
    const float* __restrict__ bias,
    _Float16* __restrict__ Hq, u32t* FlagA, u32t* FlagB, u32t* XccTab) {
  // LDS: Hs [16][HROW_] fp16 (16,512) | Rs float[4][512] (8,192) |
  // xl u32[128] (512) | go u32 | pcnt u32 = 25,224 used; padded to 96 KB.
  __shared__ __align__(16) char smem[98304];
  _Float16* Hs = (_Float16*)smem;
  float* Rs = (float*)(smem + 16512);
  u32t* xl = (u32t*)(smem + 24704);
  volatile u32t* goP = (volatile u32t*)(smem + 25216);
  u32t* pcntP = (u32t*)(smem + 25220);

  const int bid = blockIdx.x;
  const int d = bid & 7;    // domain: rows d*16 .. d*16+15 (one XCD, verified)
  const int s = bid >> 3;   // unit slice: units s*32 .. s*32+31
  const int tid = threadIdx.x;
  const int lane = tid & 63;
  const int wave = tid >> 6;      // 8 waves
  const int p16 = lane & 15;
  const int quad = lane >> 4;
  const int sg = wave & 3;        // unit subgroup (8 units)
  const int kh = wave >> 2;       // 0: exchange + h[0,256) + epilogue
                                  // 1: x-GEMM + h[256,512)

  // ---- one-time XCD-mapping probe (gates the L2-local DATA path) ----
  // hwreg(HW_REG_XCC_ID=20, offset=0, size=32) -> imm = (31<<11)|20 = 63508
  if (tid == 0) {
    *goP = 0u;
    *pcntP = 0u;
    u32t myx = (u32t)__builtin_amdgcn_s_getreg(63508) & 0xFFu;
    __hip_atomic_store(XccTab + bid, 0x5A5A0000u | myx, __ATOMIC_RELAXED,
                       __HIP_MEMORY_SCOPE_AGENT);
  }
  if (wave == 0) {
    u32t v0, v1;
    for (;;) {
      v0 = __hip_atomic_load(XccTab + lane, __ATOMIC_RELAXED,
                             __HIP_MEMORY_SCOPE_AGENT);
      v1 = __hip_atomic_load(XccTab + 64 + lane, __ATOMIC_RELAXED,
                             __HIP_MEMORY_SCOPE_AGENT);
      if (__all(((v0 >> 16) == 0x5A5Au) & ((v1 >> 16) == 0x5A5Au))) break;
      __builtin_amdgcn_s_sleep(8);
    }
    xl[lane] = v0;
    xl[lane + 64] = v1;
  }
  __syncthreads();
  int fastv;
  {
    const u32t ref = xl[d];
    bool dom = true;
    for (int j = 1; j < 16; ++j) dom = dom && (xl[d + 8 * j] == ref);
    bool sane = false;  // getreg sanity: a constant-reading getreg -> slow
    const u32t z0 = xl[0];
    for (int e = 1; e < 128; ++e) sane = sane || (xl[e] != z0);
    fastv = (dom && sane) ? 1 : 0;
  }
  const bool fastp = (bool)__builtin_amdgcn_readfirstlane(fastv);

  // ---- one-time: gather this wave's B-fragments into VGPRs ----
  // (UNCHANGED from R22: with operands swapped, this same data serves as
  //  the A'-fragment A'[m=lane&15][k=quad*4+j] = W[gk][C(m)].)
  const int C0 = ((p16 >> 3) & 1) * 512 + s * 32 + sg * 8 + (p16 & 7);  // i/f
  const int C1 = C0 + 1024;                                             // g/o
  half4 b0r[32], b1r[32];
  if (kh == 0) {
#pragma unroll
    for (int i = 0; i < 16; ++i) {
      int kb = 16 + i;
#pragma unroll
      for (int j = 0; j < 4; ++j) {
        int gk = kb * 16 + quad * 4 + j;
        b0r[i][j] = (_Float16)Wh[(size_t)(gk - E_) * 2048 + C0];
        b1r[i][j] = (_Float16)Wh[(size_t)(gk - E_) * 2048 + C1];
      }
    }
  } else {
#pragma unroll
    for (int i = 0; i < 32; ++i) {
      int kb = (i < 16) ? i : (16 + i);
#pragma unroll
      for (int j = 0; j < 4; ++j) {
        int gk = kb * 16 + quad * 4 + j;
        float w0 = (gk < E_) ? Wx[(size_t)gk * 2048 + C0]
                             : Wh[(size_t)(gk - E_) * 2048 + C0];
        float w1 = (gk < E_) ? Wx[(size_t)gk * 2048 + C1]
                             : Wh[(size_t)(gk - E_) * 2048 + C1];
        b0r[i][j] = (_Float16)w0;
        b1r[i][j] = (_Float16)w1;
      }
    }
  }

  // ---- transposed-epilogue constants (kh0) ----
  // lane (p16=batch row, quad): units u0..u0+3, u0 = s*32+sg*8+(quad&1)*4.
  // quad0/1 lanes own i(acc0)/g(acc1); quad2/3 hold f/o for the same units.
  const int u0 = s * 32 + sg * 8 + (quad & 1) * 4;
  const floatx4 bi = *(const floatx4*)(bias + u0);          // i
  const floatx4 bf = *(const floatx4*)(bias + 512 + u0);    // f
  const floatx4 bg = *(const floatx4*)(bias + 1024 + u0);   // g
  const floatx4 bo = *(const floatx4*)(bias + 1536 + u0);   // o

  float cst[4] = {0.f, 0.f, 0.f, 0.f};  // c-state (kh0, quad<2 lanes)

  const int brow = d * 16 + p16;   // x/h fragment batch row
  const int ko = quad * 4;

  for (int t = 0; t < T_; ++t) {
    const int pin = t & 1, pout = pin ^ 1;

    floatx4 acc0 = {0.f, 0.f, 0.f, 0.f};
    floatx4 acc1 = {0.f, 0.f, 0.f, 0.f};

    if (kh == 1) {
      // ---- x-GEMM (kh1 only): 16 K16-blocks, operands swapped ----
      const _Float16* xr = X + ((size_t)t * B_ + brow) * E_ + ko;
#pragma unroll
      for (int i = 0; i < 16; ++i) {
        half4 a = *(const half4*)(xr + i * 16);
        acc0 = MFMA16(b0r[i], a, acc0, 0, 0, 0);
        acc1 = MFMA16(b1r[i], a, acc1, 0, 0, 0);
      }
    } else if (t > 0) {
      // ---- exchange (kh0 only): gate + bulk + stage, overlaps kh1's x ----
      const u32t tgt = (u32t)t;
      if (wave == 0) {
        // wave 0 is the sole poller (16 lanes, 16 distinct flag words).
        u32t v;
        if (fastp) {
          u32t* fa = FlagA + (size_t)(pin * 8 + d) * 16;
          const u32t* fb = FlagB + (size_t)(pin * 8 + d) * 16;
          int budget = 512;   // R21-proven RMW channel; fallback = hang guard
          for (;;) {
            if (budget > 0) {
              u32t old = tgt;
              if (lane < 16) {
                u32t* ap = fa + lane;
                asm volatile(
                    "global_atomic_add %0, %1, %2, off sc0\n\t"
                    "s_waitcnt vmcnt(0)"
                    : "=&v"(old) : "v"(ap), "v"(0u) : "memory");
              }
              v = old;
            } else {
              v = (lane < 16)
                      ? __hip_atomic_load(fb + lane, __ATOMIC_RELAXED,
                                          __HIP_MEMORY_SCOPE_AGENT)
                      : tgt;
            }
            if (__all(v == tgt)) break;
            --budget;
            if (budget < 500) __builtin_amdgcn_s_sleep(1);
          }
        } else {
          const u32t* fb = FlagB + (size_t)(pin * 8 + d) * 16;
          for (;;) {
            v = (lane < 16)
                    ? __hip_atomic_load(fb + lane, __ATOMIC_RELAXED,
                                        __HIP_MEMORY_SCOPE_AGENT)
                    : tgt;
            if (__all(v == tgt)) break;
            __builtin_amdgcn_s_sleep(1);
          }
        }
        if (lane == 0) *goP = tgt;   // LDS release for waves 1-3
      } else {
        // waves 1-3: LDS gate (wave0 wrote go=t after data-safe flag).
        u32t g;
        do { g = *goP; } while (g < tgt);
      }

      // bulk: 4 rows/wave (rows wave*4 .. wave*4+3), 8 chunks of 512B
      const _Float16* hq = Hq + ((size_t)(pin * 8 + d) * 16 + wave * 4) * 512;
      u64t hv[8];
      if (fastp) {
        // ONE asm block: 8 pipelined sc0 loads (imm offsets), one vmcnt(0).
        const u64t* hqb = (const u64t*)hq + lane;
        u64t h0, h1, h2, h3, h4, h5, h6, h7;
        asm volatile(
            "global_load_dwordx2 %0, %8, off sc0\n\t"
            "global_load_dwordx2 %1, %8, off offset:512 sc0\n\t"
            "global_load_dwordx2 %2, %8, off offset:1024 sc0\n\t"
            "global_load_dwordx2 %3, %8, off offset:1536 sc0\n\t"
            "global_load_dwordx2 %4, %8, off offset:2048 sc0\n\t"
            "global_load_dwordx2 %5, %8, off offset:2560 sc0\n\t"
            "global_load_dwordx2 %6, %8, off offset:3072 sc0\n\t"
            "global_load_dwordx2 %7, %8, off offset:3584 sc0\n\t"
            "s_waitcnt vmcnt(0)"
            : "=&v"(h0), "=&v"(h1), "=&v"(h2), "=&v"(h3),
              "=&v"(h4), "=&v"(h5), "=&v"(h6), "=&v"(h7)
            : "v"(hqb)
            : "memory");
        hv[0] = h0; hv[1] = h1; hv[2] = h2; hv[3] = h3;
        hv[4] = h4; hv[5] = h5; hv[6] = h6; hv[7] = h7;
      } else {
#pragma unroll
        for (int j = 0; j < 8; ++j) {
          size_t idx = (size_t)(j >> 1) * 128 + (j & 1) * 64 + lane;
          hv[j] = __hip_atomic_load((const u64t*)hq + idx, __ATOMIC_RELAXED,
                                    __HIP_MEMORY_SCOPE_AGENT);
        }
      }
#pragma unroll
      for (int j = 0; j < 8; ++j) {
        int r = wave * 4 + (j >> 1), half = j & 1;
        *(u64t*)(Hs + r * HROW_ + half * 256 + lane * 4) = hv[j];
      }
    }
    __syncthreads();  // B2: slab ready + x partial-accs in flight

    if (t > 0) {
      // ---- h-GEMM from slab (operands swapped; reads unchanged) ----
#pragma unroll
      for (int i = 0; i < 16; ++i) {
        int hk = kh * 16 + i;
        half4 a = *(const half4*)(Hs + p16 * HROW_ + hk * 16 + ko);
        const int wi = (kh == 0) ? i : (16 + i);
        acc0 = MFMA16(b0r[wi], a, acc0, 0, 0, 0);
        acc1 = MFMA16(b1r[wi], a, acc1, 0, 0, 0);
      }
    }

    // ---- kh1 partials -> Rs (same transposed layout both kh groups) ----
    if (kh == 1) {
      float* wb = Rs + sg * 512;
      *(floatx4*)(wb + lane * 4) = acc0;
      *(floatx4*)(wb + 256 + lane * 4) = acc1;
    }
    __syncthreads();  // B3: partials ready. kh1 then free-runs to t+1.

    // ---- epilogue (kh0): transposed — packed 8B h store per lane ----
    if (kh == 0) {
      const float* rb = Rs + sg * 512;
      floatx4 z0v = acc0 + *(const floatx4*)(rb + lane * 4);      // i | f
      floatx4 z1v = acc1 + *(const floatx4*)(rb + 256 + lane * 4); // g | o
      half4 hp4;
#pragma unroll
      for (int r = 0; r < 4; ++r) {
        float fraw = __shfl_xor(z0v[r], 32, 64);  // partner's f (quad<2 rx)
        float oraw = __shfl_xor(z1v[r], 32, 64);  // partner's o
        float iv = sigmf(z0v[r] + bi[r]);
        float gv = tanh_f(z1v[r] + bg[r]);
        float fv = sigmf(fraw + bf[r]);
        float ov = sigmf(oraw + bo[r]);
        float cn = fv * cst[r] + iv * gv;
        cst[r] = cn;
        hp4[r] = (_Float16)(ov * tanh_f(cn));
      }
      if (quad < 2) {
        // h for units u0..u0+3 of batch row p16: ONE contiguous 8B store.
        u64t pk = __builtin_bit_cast(u64t, hp4);
        u64t* hp =
            (u64t*)(Hq + ((size_t)(pout * 8 + d) * 16 + p16) * 512 + u0);
        if (fastp) {
          *hp = pk;  // plain: L1 write-through -> dirty in local XCD-L2
        } else {
          __hip_atomic_store(hp, pk, __ATOMIC_RELAXED,
                             __HIP_MEMORY_SCOPE_AGENT);
        }
      }

      // ---- publish: per-wave drain + LDS counter (R22-proven) ----
      asm volatile("s_waitcnt vmcnt(0)" ::: "memory");
      __builtin_amdgcn_sched_barrier(0);
      if (lane == 0) {
        u32t old = atomicAdd(pcntP, 1u);
        if (old == (u32t)(4 * t + 3)) {
          size_t fo = (size_t)(pout * 8 + d) * 16 + s;
          if (fastp) {
            u32t* ap = FlagA + fo;
            u32t nv = (u32t)(t + 1);
            asm volatile("global_atomic_swap %0, %1, off"
                         :: "v"(ap), "v"(nv) : "memory");
          }
          __hip_atomic_store(FlagB + fo, (u32t)(t + 1), __ATOMIC_RELAXED,
                             __HIP_MEMORY_SCOPE_AGENT);  // progress channel
        }
      }
    }
  }
}

// MLP head: one block per batch row. h(512)->relu 128->relu 64->sigmoid 1.
// T=512 even -> final h in Hq parity 0. Kernel boundary orders prior stores
// (end-of-dispatch agent release writes back dirty L2 lines).
__global__ void head_kernel(const _Float16* __restrict__ Hq,
                            const float* __restrict__ W1, const float* __restrict__ b1,
                            const float* __restrict__ W2, const float* __restrict__ b2,
                            const float* __restrict__ W3, const float* __restrict__ b3,
                            float* __restrict__ out) {
  __shared__ float hs[512];
  __shared__ float h1[128];
  __shared__ float h2[64];
  int row = blockIdx.x;
  int tid = threadIdx.x;  // 128 threads
  int dd = row >> 4, rr = row & 15;
  const _Float16* hrow = Hq + ((size_t)dd * 16 + rr) * 512;
  for (int k = tid; k < 512; k += 128) hs[k] = (float)hrow[k];
  __syncthreads();
  float a = b1[tid];
  for (int k = 0; k < 512; ++k) a += hs[k] * W1[k * 128 + tid];
  h1[tid] = fmaxf(a, 0.0f);
  __syncthreads();
  if (tid < 64) {
    float a2 = b2[tid];
    for (int k = 0; k < 128; ++k) a2 += h1[k] * W2[k * 64 + tid];
    h2[tid] = fmaxf(a2, 0.0f);
  }
  __syncthreads();
  if (tid == 0) {
    float a3 = b3[0];
    for (int k = 0; k < 64; ++k) a3 += h2[k] * W3[k];
    out[row] = 1.0f / (1.0f + __expf(-a3));
  }
}

extern "C" void kernel_launch(void* const* d_in, const int* in_sizes, int n_in,
                              void* d_out, int out_size, void* d_ws, size_t ws_size,
                              hipStream_t stream) {
  const int* sent = (const int*)d_in[0];
  const float* emb = (const float*)d_in[1];
  const float* Wx = (const float*)d_in[2];
  const float* Wh = (const float*)d_in[3];
  const float* b = (const float*)d_in[4];
  const float* W1 = (const float*)d_in[5];
  const float* b1 = (const float*)d_in[6];
  const float* W2 = (const float*)d_in[7];
  const float* b2 = (const float*)d_in[8];
  const float* W3 = (const float*)d_in[9];
  const float* b3 = (const float*)d_in[10];
  float* out = (float*)d_out;

  char* ws = (char*)d_ws;
  _Float16* X = (_Float16*)(ws);
  _Float16* Hq = (_Float16*)(ws + (size_t)33554432);
  u32t* FlagA = (u32t*)(ws + (size_t)33554432 + 262144);
  u32t* FlagB = (u32t*)(ws + (size_t)33554432 + 263168);
  u32t* XccTab = (u32t*)(ws + (size_t)33554432 + 264192);

  // Zero FlagA+FlagB+XccTab (contiguous 2,560 B) every launch:
  // removes the first-launch garbage hazard; 0 never matches t in [1,512].
  hipMemsetAsync(FlagA, 0, 2560, stream);
  prep_x_kernel<<<8192, 256, 0, stream>>>(sent, emb, X);
  lstm_kernel<<<NWG_, 512, 0, stream>>>(X, Wx, Wh, b, Hq, FlagA, FlagB, XccTab);
  head_kernel<<<128, 128, 0, stream>>>(Hq, W1, b1, W2, b2, W3, b3, out);
}